// Round 5
// baseline (175.596 us; speedup 1.0000x reference)
//
#include <hip/hip_runtime.h>
#include <hip/hip_cooperative_groups.h>
#include <hip/hip_bf16.h>
#include <math.h>

namespace cg = cooperative_groups;

// Problem constants: B=16, C=64, H=W=64, M=4096
#define KS 16
#define CHUNK 256
#define PART_STRIDE 4224   // 4096 S + 64 rsum + 1 T-partial + pad

typedef __attribute__((ext_vector_type(8))) short short8;
typedef __attribute__((ext_vector_type(4))) float floatx4;

__device__ __forceinline__ unsigned short f2bf(float f) {
    __hip_bfloat16 h = __float2bfloat16(f);
    return *reinterpret_cast<unsigned short*>(&h);
}
__device__ __forceinline__ float bf2f(unsigned short h) {
    return __uint_as_float(((unsigned int)h) << 16);
}
// Halfword base of element (r, k=8*kb) in the swizzled fragment layout.
__device__ __forceinline__ int HW(int r, int kb) {
    return ((kb << 6) + (r ^ (kb & 15))) << 3;
}
__device__ __forceinline__ floatx4 mfma_bf16(short8 a, short8 b, floatx4 c) {
    return __builtin_amdgcn_mfma_f32_16x16x32_bf16(a, b, c, 0, 0, 0);
}

// ---------------------------------------------------------------------------
// NS pass helpers, 4 waves (256 thr). Stored matrices are transposed products
// (valid: all NS iterates are symmetric). MODE 0: D=0.5*(3I-P)  1: D=P
// ---------------------------------------------------------------------------
template <int MODE>
__device__ __forceinline__ void pass_single(const unsigned short (*U)[4096],
                                            const unsigned short (*V)[4096],
                                            unsigned short (*D)[4096], int tid) {
    int lane = tid & 63, wv = tid >> 6;
    int g = lane >> 4, rh = lane & 15;
    int ta0 = (wv >> 1) << 1, tc0 = (wv & 1) << 1;
    floatx4 acc[2][2];
    #pragma unroll
    for (int a = 0; a < 2; ++a)
        #pragma unroll
        for (int c = 0; c < 2; ++c)
            acc[a][c] = (floatx4){0.f, 0.f, 0.f, 0.f};

    #pragma unroll
    for (int ks_ = 0; ks_ < 2; ++ks_) {
        int kb = ks_ * 4 + g;
        short8 auh[2], aul[2], bvh[2], bvl[2];
        #pragma unroll
        for (int a = 0; a < 2; ++a) {
            int o = HW(16 * (ta0 + a) + rh, kb);
            auh[a] = *reinterpret_cast<const short8*>(&U[0][o]);
            aul[a] = *reinterpret_cast<const short8*>(&U[1][o]);
        }
        #pragma unroll
        for (int c = 0; c < 2; ++c) {
            int o = HW(16 * (tc0 + c) + rh, kb);
            bvh[c] = *reinterpret_cast<const short8*>(&V[0][o]);
            bvl[c] = *reinterpret_cast<const short8*>(&V[1][o]);
        }
        #pragma unroll
        for (int a = 0; a < 2; ++a)
            #pragma unroll
            for (int c = 0; c < 2; ++c) {
                acc[a][c] = mfma_bf16(auh[a], bvh[c], acc[a][c]);
                acc[a][c] = mfma_bf16(auh[a], bvl[c], acc[a][c]);
                acc[a][c] = mfma_bf16(aul[a], bvh[c], acc[a][c]);
            }
    }

    #pragma unroll
    for (int a = 0; a < 2; ++a) {
        int ta = ta0 + a;
        int kbi = 2 * ta + (g >> 1), sub = (g & 1) << 2;
        #pragma unroll
        for (int c = 0; c < 2; ++c) {
            int j = 16 * (tc0 + c) + rh;
            unsigned short hs[4], ls[4];
            #pragma unroll
            for (int qq = 0; qq < 4; ++qq) {
                int i = 16 * ta + 4 * g + qq;
                float v = acc[a][c][qq];
                if (MODE == 0) v = 0.5f * ((i == j ? 3.0f : 0.0f) - v);
                hs[qq] = f2bf(v);
                ls[qq] = f2bf(v - bf2f(hs[qq]));
            }
            int idx = HW(j, kbi) + sub;   // transposed position (j, i)
            uint2 u;
            u.x = hs[0] | ((unsigned)hs[1] << 16); u.y = hs[2] | ((unsigned)hs[3] << 16);
            *reinterpret_cast<uint2*>(&D[0][idx]) = u;
            u.x = ls[0] | ((unsigned)ls[1] << 16); u.y = ls[2] | ((unsigned)ls[3] << 16);
            *reinterpret_cast<uint2*>(&D[1][idx]) = u;
        }
    }
    __syncthreads();
}

// Fused dual pass: waves 0-1 compute DY = Y@W, waves 2-3 compute DZ = W@Z.
__device__ __forceinline__ void pass_fused(const unsigned short (*Y)[4096],
                                           const unsigned short (*W)[4096],
                                           const unsigned short (*Z)[4096],
                                           unsigned short (*DY)[4096],
                                           unsigned short (*DZ)[4096], int tid) {
    int lane = tid & 63, wv = tid >> 6;
    int g = lane >> 4, rh = lane & 15;
    const unsigned short (*U)[4096] = (wv < 2) ? Y : W;
    const unsigned short (*V)[4096] = (wv < 2) ? W : Z;
    unsigned short (*D)[4096] = (wv < 2) ? DY : DZ;
    int ta0 = (wv & 1) << 1;
    floatx4 acc[2][4];
    #pragma unroll
    for (int a = 0; a < 2; ++a)
        #pragma unroll
        for (int c = 0; c < 4; ++c)
            acc[a][c] = (floatx4){0.f, 0.f, 0.f, 0.f};

    #pragma unroll
    for (int ks_ = 0; ks_ < 2; ++ks_) {
        int kb = ks_ * 4 + g;
        short8 bvh[4], bvl[4];
        #pragma unroll
        for (int c = 0; c < 4; ++c) {
            int o = HW(16 * c + rh, kb);
            bvh[c] = *reinterpret_cast<const short8*>(&V[0][o]);
            bvl[c] = *reinterpret_cast<const short8*>(&V[1][o]);
        }
        #pragma unroll
        for (int a = 0; a < 2; ++a) {
            int o = HW(16 * (ta0 + a) + rh, kb);
            short8 auh = *reinterpret_cast<const short8*>(&U[0][o]);
            short8 aul = *reinterpret_cast<const short8*>(&U[1][o]);
            #pragma unroll
            for (int c = 0; c < 4; ++c) {
                acc[a][c] = mfma_bf16(auh, bvh[c], acc[a][c]);
                acc[a][c] = mfma_bf16(auh, bvl[c], acc[a][c]);
                acc[a][c] = mfma_bf16(aul, bvh[c], acc[a][c]);
            }
        }
    }

    #pragma unroll
    for (int a = 0; a < 2; ++a) {
        int ta = ta0 + a;
        int kbi = 2 * ta + (g >> 1), sub = (g & 1) << 2;
        #pragma unroll
        for (int c = 0; c < 4; ++c) {
            int j = 16 * c + rh;
            unsigned short hs[4], ls[4];
            #pragma unroll
            for (int qq = 0; qq < 4; ++qq) {
                float v = acc[a][c][qq];
                hs[qq] = f2bf(v);
                ls[qq] = f2bf(v - bf2f(hs[qq]));
            }
            int idx = HW(j, kbi) + sub;
            uint2 u;
            u.x = hs[0] | ((unsigned)hs[1] << 16); u.y = hs[2] | ((unsigned)hs[3] << 16);
            *reinterpret_cast<uint2*>(&D[0][idx]) = u;
            u.x = ls[0] | ((unsigned)ls[1] << 16); u.y = ls[2] | ((unsigned)ls[3] << 16);
            *reinterpret_cast<uint2*>(&D[1][idx]) = u;
        }
    }
    __syncthreads();
}

__device__ __forceinline__ void colsum_stage(const unsigned short (*M)[4096],
                                             float* dst, float* part, int tid) {
    int ii = tid & 63, grp = tid >> 6;
    #pragma unroll
    for (int h = 0; h < 2; ++h) {
        int gg = grp + 4 * h;
        int o = HW(ii, gg);
        short8 vh = *reinterpret_cast<const short8*>(&M[0][o]);
        short8 vl = *reinterpret_cast<const short8*>(&M[1][o]);
        float s = 0.f;
        #pragma unroll
        for (int e = 0; e < 8; ++e)
            s += bf2f((unsigned short)vh[e]) + bf2f((unsigned short)vl[e]);
        part[gg * 64 + ii] = s;
    }
    __syncthreads();
    if (tid < 64) {
        float s = 0.f;
        #pragma unroll
        for (int q = 0; q < 8; ++q) s += part[q * 64 + tid];
        dst[tid] = s;
    }
    __syncthreads();
}

__device__ __forceinline__ void matvec_stage(const unsigned short (*M)[4096],
                                             const float* __restrict__ src,
                                             float* dst, float* part, int tid) {
    int ii = tid & 63, grp = tid >> 6;
    #pragma unroll
    for (int h = 0; h < 2; ++h) {
        int gg = grp + 4 * h;
        int o = HW(ii, gg);
        short8 vh = *reinterpret_cast<const short8*>(&M[0][o]);
        short8 vl = *reinterpret_cast<const short8*>(&M[1][o]);
        float s = 0.f;
        #pragma unroll
        for (int e = 0; e < 8; ++e)
            s += (bf2f((unsigned short)vh[e]) + bf2f((unsigned short)vl[e])) * src[gg * 8 + e];
        part[gg * 64 + ii] = s;
    }
    __syncthreads();
    if (tid < 64) {
        float s = 0.f;
        #pragma unroll
        for (int q = 0; q < 8; ++q) s += part[q * 64 + tid];
        dst[tid] = s;
    }
    __syncthreads();
}

// ---------------------------------------------------------------------------
// Single cooperative kernel: A) partial Gram  B) spread reduce+convert
// C) Newton-Schulz + conv chain (blocks 0-15)  D) elementwise scale.
// 88KB LDS -> exactly 1 block/CU -> 256 blocks spread over all 256 CUs.
// ---------------------------------------------------------------------------
__global__ __launch_bounds__(256, 1) void soca_fused(const float* __restrict__ x,
                                                     const float* __restrict__ w1,
                                                     const float* __restrict__ b1,
                                                     const float* __restrict__ w2,
                                                     const float* __restrict__ b2,
                                                     float* __restrict__ out,
                                                     float* __restrict__ ws) {
    cg::grid_group grid = cg::this_grid();
    __shared__ __align__(16) unsigned char big[81920];   // A: xh/xl  C: 5x2 planes
    __shared__ __align__(16) float auxf[1536];
    int bk = blockIdx.x, tid = threadIdx.x;
    int lane = tid & 63, wv = tid >> 6;
    const float invM = 1.0f / 4096.0f;

    unsigned short* planesG = (unsigned short*)(ws + (size_t)256 * PART_STRIDE);
    float* normAG = (float*)(planesG + 16 * 4 * 4096);
    float* ctr1 = normAG + 16;
    float* ctr2 = ctr1 + 4096;
    float* s_area = ctr2 + 4096;

    // ================= Phase A: partial Gram per (b, ks) chunk ==============
    {
        int b = bk >> 4, ks = bk & 15;
        unsigned short* xh = (unsigned short*)big;
        unsigned short* xl = xh + 64 * CHUNK;
        float* csp = auxf;              // [4][256]
        float* rs_part = auxf + 1024;   // [4][64]
        float* red = auxf + 1280;       // [256]
        const float* xb = x + ((size_t)b * 64) * 4096 + ks * CHUNK;

        int kbw = lane >> 1, wsub = (lane & 1) << 2;
        float cs0 = 0.f, cs1 = 0.f, cs2 = 0.f, cs3 = 0.f;
        #pragma unroll
        for (int r = 0; r < 16; ++r) {
            int c = wv * 16 + r;
            float4 v = *reinterpret_cast<const float4*>(xb + (size_t)c * 4096 + lane * 4);
            cs0 += v.x; cs1 += v.y; cs2 += v.z; cs3 += v.w;
            float vv[4] = {v.x, v.y, v.z, v.w};
            unsigned short hs[4], ls[4];
            #pragma unroll
            for (int q = 0; q < 4; ++q) {
                hs[q] = f2bf(vv[q]);
                ls[q] = f2bf(vv[q] - bf2f(hs[q]));
            }
            int idx = HW(c, kbw) + wsub;
            uint2 u;
            u.x = hs[0] | ((unsigned)hs[1] << 16); u.y = hs[2] | ((unsigned)hs[3] << 16);
            *reinterpret_cast<uint2*>(&xh[idx]) = u;
            u.x = ls[0] | ((unsigned)ls[1] << 16); u.y = ls[2] | ((unsigned)ls[3] << 16);
            *reinterpret_cast<uint2*>(&xl[idx]) = u;
        }
        *reinterpret_cast<float4*>(&csp[wv * 256 + lane * 4]) = make_float4(cs0, cs1, cs2, cs3);
        __syncthreads();

        float cm = csp[tid] + csp[256 + tid] + csp[512 + tid] + csp[768 + tid];

        int g = lane >> 4, rh = lane & 15;
        int ta0 = (wv >> 1) << 1, tc0 = (wv & 1) << 1;
        floatx4 acc[2][2];
        #pragma unroll
        for (int a = 0; a < 2; ++a)
            #pragma unroll
            for (int c = 0; c < 2; ++c)
                acc[a][c] = (floatx4){0.f, 0.f, 0.f, 0.f};

        #pragma unroll
        for (int ks_ = 0; ks_ < 8; ++ks_) {
            int kb = ks_ * 4 + g;
            short8 ah[2], al[2], bh[2], bl[2];
            #pragma unroll
            for (int a = 0; a < 2; ++a) {
                int o = HW(16 * (ta0 + a) + rh, kb);
                ah[a] = *reinterpret_cast<const short8*>(&xh[o]);
                al[a] = *reinterpret_cast<const short8*>(&xl[o]);
            }
            #pragma unroll
            for (int c = 0; c < 2; ++c) {
                int o = HW(16 * (tc0 + c) + rh, kb);
                bh[c] = *reinterpret_cast<const short8*>(&xh[o]);
                bl[c] = *reinterpret_cast<const short8*>(&xl[o]);
            }
            #pragma unroll
            for (int a = 0; a < 2; ++a)
                #pragma unroll
                for (int c = 0; c < 2; ++c) {
                    acc[a][c] = mfma_bf16(ah[a], bh[c], acc[a][c]);
                    acc[a][c] = mfma_bf16(ah[a], bl[c], acc[a][c]);
                    acc[a][c] = mfma_bf16(al[a], bh[c], acc[a][c]);
                }
        }

        float* outp = ws + (size_t)bk * PART_STRIDE;
        #pragma unroll
        for (int a = 0; a < 2; ++a)
            #pragma unroll
            for (int c = 0; c < 2; ++c) {
                int j = 16 * (tc0 + c) + rh;
                int i0 = 16 * (ta0 + a) + 4 * g;
                *reinterpret_cast<float4*>(&outp[j * 64 + i0]) =
                    make_float4(acc[a][c][0], acc[a][c][1], acc[a][c][2], acc[a][c][3]);
            }

        {   // partial row sums from staged planes (hi+lo ~ fp32)
            float s = 0.f;
            #pragma unroll
            for (int m = 0; m < 8; ++m) {
                int o = HW(lane, wv * 8 + m);
                short8 vh = *reinterpret_cast<const short8*>(&xh[o]);
                short8 vl = *reinterpret_cast<const short8*>(&xl[o]);
                #pragma unroll
                for (int e = 0; e < 8; ++e)
                    s += bf2f((unsigned short)vh[e]) + bf2f((unsigned short)vl[e]);
            }
            rs_part[wv * 64 + lane] = s;
        }
        red[tid] = cm * cm;
        __syncthreads();
        for (int st = 128; st > 0; st >>= 1) {
            if (tid < st) red[tid] += red[tid + st];
            __syncthreads();
        }
        if (tid < 64)
            outp[4096 + tid] = rs_part[tid] + rs_part[64 + tid] + rs_part[128 + tid] + rs_part[192 + tid];
        if (tid == 0) outp[4160] = red[0];
        __threadfence();
    }
    grid.sync();

    // ========== Phase B: spread reduce + center + convert to planes =========
    {
        int b = bk >> 4, q = bk & 15;
        const float* base = ws + (size_t)b * KS * PART_STRIDE;
        float* rsum = auxf;   // [64]; auxf[64]=T, auxf[65]=normA
        if (tid < 64) {
            float s = 0.f;
            for (int k = 0; k < KS; ++k) s += base[k * PART_STRIDE + 4096 + tid];
            rsum[tid] = s;
        } else if (tid == 64) {
            float t = 0.f;
            for (int k = 0; k < KS; ++k) t += base[k * PART_STRIDE + 4160];
            auxf[64] = t;
        }
        __syncthreads();
        if (tid == 0) {
            float sr = 0.f;
            for (int i = 0; i < 64; ++i) sr += rsum[i];
            float nA = (auxf[64] - sr * sr * invM) * invM;
            auxf[65] = nA;
            if (q == 0) normAG[b] = nA;
        }
        __syncthreads();
        float invNA = 1.0f / auxf[65];
        int e = q * 256 + tid, i = e >> 6, j = e & 63;
        float S = 0.f;
        for (int k = 0; k < KS; ++k) S += base[k * PART_STRIDE + e];
        float cv = S * invM - (rsum[i] * invM) * (rsum[j] * invM);
        float a = cv * invNA;
        float z = 0.5f * ((i == j ? 3.0f : 0.0f) - a);
        unsigned short ah = f2bf(a), al_ = f2bf(a - bf2f(ah));
        unsigned short zh = f2bf(z), zl = f2bf(z - bf2f(zh));
        unsigned short* pg = planesG + (size_t)b * 4 * 4096;
        pg[e] = ah; pg[4096 + e] = al_; pg[8192 + e] = zh; pg[12288 + e] = zl;

        if (bk < 16) {          // gather conv1 center taps -> ctr1[i*64+o]
            int t = bk * 256 + tid, i2 = t >> 6, o2 = t & 63;
            ctr1[t] = w1[(o2 * 64 + i2) * 9 + 4];
        } else if (bk < 32) {   // conv2
            int t = (bk - 16) * 256 + tid, i2 = t >> 6, o2 = t & 63;
            ctr2[t] = w2[(o2 * 64 + i2) * 9 + 4];
        }
        __threadfence();
    }
    grid.sync();

    // ================= Phase C: Newton-Schulz (blocks 0-15) =================
    if (bk < 16) {
        int b = bk;
        unsigned short (*planes)[2][4096] = (unsigned short (*)[2][4096])big;
        unsigned short* pbase = (unsigned short*)big;
        const uint4* src = reinterpret_cast<const uint4*>(planesG + (size_t)b * 4 * 4096);
        #pragma unroll
        for (int it = 0; it < 8; ++it) {
            int lin = it * 256 + tid;       // uint4 index, 2048 total
            uint4 v = src[lin];
            int pl = lin >> 9, within = lin & 511;
            int i = within >> 3, kb = within & 7;
            int dst = (pl >> 1) * 8192 + (pl & 1) * 4096 + HW(i, kb);
            *reinterpret_cast<uint4*>(&pbase[dst]) = v;
        }
        __syncthreads();

        pass_single<1>(planes[0], planes[1], planes[2], tid);   // Y0 = A@Z0
        pass_single<0>(planes[1], planes[2], planes[0], tid);   // W1
        pass_fused(planes[2], planes[0], planes[1], planes[3], planes[4], tid); // Y1,Z1
        pass_single<0>(planes[4], planes[3], planes[1], tid);   // W2
        pass_fused(planes[3], planes[1], planes[4], planes[2], planes[0], tid); // Y2,Z2
        pass_single<0>(planes[0], planes[2], planes[3], tid);   // W3
        pass_single<1>(planes[2], planes[3], planes[4], tid);   // Y3 = Y2@W3

        float* part = auxf;           // 512
        float* uvec = auxf + 512;
        float* avec = auxf + 576;
        float* pvec = auxf + 640;
        float* wvec = auxf + 704;
        float* ych  = auxf + 768;
        float* hid  = auxf + 832;
        colsum_stage(planes[4], uvec, part, tid);          // u = colsum(Y3)
        matvec_stage(planes[0], uvec, avec, part, tid);    // a = Z2 u
        matvec_stage(planes[3], avec, pvec, part, tid);    // p = W3 a
        matvec_stage(planes[4], pvec, wvec, part, tid);    // w = Y3 p

        float normA = normAG[b];
        if (tid < 64)
            ych[tid] = (3.0f * uvec[tid] - wvec[tid]) * (0.5f / 64.0f) * sqrtf(normA);
        __syncthreads();
        if (tid < 64) {
            float t1 = b1[tid];
            for (int i = 0; i < 64; ++i) t1 += ctr1[i * 64 + tid] * ych[i];
            hid[tid] = fmaxf(t1, 0.f);
        }
        __syncthreads();
        if (tid < 64) {
            float t2 = b2[tid];
            for (int i = 0; i < 64; ++i) t2 += ctr2[i * 64 + tid] * hid[i];
            s_area[b * 64 + tid] = 1.0f / (1.0f + expf(-t2));
        }
        __threadfence();
    }
    grid.sync();

    // ================= Phase D: out = s[b,c] * x =================
    {
        const float4* xi = reinterpret_cast<const float4*>(x);
        float4* oo = reinterpret_cast<float4*>(out);
        int idx0 = bk * 256 + tid;
        #pragma unroll 4
        for (int f = idx0; f < 1048576; f += 65536) {
            float sv = s_area[f >> 10];
            float4 v = xi[f];
            oo[f] = make_float4(v.x * sv, v.y * sv, v.z * sv, v.w * sv);
        }
    }
}

extern "C" void kernel_launch(void* const* d_in, const int* in_sizes, int n_in,
                              void* d_out, int out_size, void* d_ws, size_t ws_size,
                              hipStream_t stream) {
    const float* x  = (const float*)d_in[0];
    const float* w1 = (const float*)d_in[1];
    const float* b1 = (const float*)d_in[2];
    const float* w2 = (const float*)d_in[3];
    const float* b2 = (const float*)d_in[4];
    float* out = (float*)d_out;
    float* ws  = (float*)d_ws;

    void* args[] = {(void*)&x, (void*)&w1, (void*)&b1, (void*)&w2, (void*)&b2,
                    (void*)&out, (void*)&ws};
    hipLaunchCooperativeKernel(reinterpret_cast<void*>(soca_fused),
                               dim3(256), dim3(256), args, 0, stream);
}